// Round 14
// baseline (4089.262 us; speedup 1.0000x reference)
//
#include <hip/hip_runtime.h>
#include <cstdint>
#include <cmath>

constexpr int BATCH = 64;
constexpr int T     = 512;
constexpr int N     = 1024;
constexpr int NWG   = 256;   // persistent workgroups (== CU count)
constexpr int NG    = 32;    // batch groups (2 batches each)
constexpr int GM    = 32;    // member WGs per group

typedef float f4 __attribute__((ext_vector_type(4)));
typedef float f2 __attribute__((ext_vector_type(2)));

struct alignas(128) PadInt { int v; int pad[31]; };
__device__ PadInt g_wgf[NG][GM];  // per-(group,member) completed-step flag

// ---- MALL-coherent access helpers (bypass L1+L2) ---------------------------
__device__ __forceinline__ f4 ld_sys_x4(const float* p) {
  f4 v;
  asm volatile("global_load_dwordx4 %0, %1, off sc0 sc1" : "=v"(v) : "v"(p));
  return v;  // NOT ready until wait_vm0()
}
__device__ __forceinline__ int ld_sys_i32(const int* p) {
  int v;
  asm volatile("global_load_dword %0, %1, off sc0 sc1\n\ts_waitcnt vmcnt(0)"
               : "=v"(v) : "v"(p) : "memory");
  return v;
}
__device__ __forceinline__ void st_sys_x2(float* p, f2 v) {
  asm volatile("global_store_dwordx2 %0, %1, off sc0 sc1 nt" ::"v"(p), "v"(v)
               : "memory");
}
__device__ __forceinline__ void st_sys_i32(int* p, int v) {
  asm volatile("global_store_dword %0, %1, off sc0 sc1" ::"v"(p), "v"(v)
               : "memory");
}
__device__ __forceinline__ void wait_vm0(void) {
  asm volatile("s_waitcnt vmcnt(0)" ::: "memory");
  __builtin_amdgcn_sched_barrier(0);
}

// ---------------------------------------------------------------------------
// W_self = 0.5*(W + W^T); also re-initializes the flag state.
// ---------------------------------------------------------------------------
__global__ __launch_bounds__(256) void symm_k(const float* __restrict__ W,
                                              float* __restrict__ Ws) {
  if (blockIdx.x == 0 && blockIdx.y == 0) {
#pragma unroll
    for (int s = 0; s < 4; ++s) {
      int idx = threadIdx.x + 256 * s;  // 0..1023
      __hip_atomic_store(&g_wgf[idx >> 5][idx & 31].v, -1, __ATOMIC_RELAXED,
                         __HIP_MEMORY_SCOPE_AGENT);
    }
  }
  int j = blockIdx.x * 16 + (threadIdx.x & 15);
  int i = blockIdx.y * 16 + (threadIdx.x >> 4);
  Ws[(size_t)i * N + j] = 0.5f * (W[(size_t)i * N + j] + W[(size_t)j * N + i]);
}

// ---------------------------------------------------------------------------
// x_proj = A (M x K) . B^T, B = W_input (N x K) row-major. 128x128 tile.
// XCD-aware swizzle: each XCD owns a contiguous bm chunk x all 8 bn.
// ---------------------------------------------------------------------------
__global__ __launch_bounds__(256) void xproj_gemm(const float* __restrict__ A,
                                                  const float* __restrict__ B,
                                                  float* __restrict__ C,
                                                  int M) {
  constexpr int BM = 128, BN = 128, BK = 16;
  __shared__ float As[BK][BM + 4];
  __shared__ float Bs[BK][BN + 4];

  const int tid = threadIdx.x;
  const int lin = blockIdx.x + gridDim.x * blockIdx.y;  // 0..2047
  const int sw  = ((lin & 7) << 8) + (lin >> 3);        // bijective (2048%8==0)
  const int bm  = sw >> 3;                              // 0..255
  const int bn  = sw & 7;                               // 0..7
  const int tx = tid & 15, ty = tid >> 4;
  const int K = N;

  float acc[8][8];
#pragma unroll
  for (int i = 0; i < 8; ++i)
#pragma unroll
    for (int j = 0; j < 8; ++j) acc[i][j] = 0.f;

  for (int kt = 0; kt < K; kt += BK) {
#pragma unroll
    for (int s = 0; s < 2; ++s) {
      int f = tid + s * 256;
      int row = f >> 2, kq = f & 3;
      float4 a = *reinterpret_cast<const float4*>(
          &A[(size_t)(bm * BM + row) * K + kt + kq * 4]);
      As[kq * 4 + 0][row] = a.x;
      As[kq * 4 + 1][row] = a.y;
      As[kq * 4 + 2][row] = a.z;
      As[kq * 4 + 3][row] = a.w;
      float4 b = *reinterpret_cast<const float4*>(
          &B[(size_t)(bn * BN + row) * K + kt + kq * 4]);
      Bs[kq * 4 + 0][row] = b.x;
      Bs[kq * 4 + 1][row] = b.y;
      Bs[kq * 4 + 2][row] = b.z;
      Bs[kq * 4 + 3][row] = b.w;
    }
    __syncthreads();

#pragma unroll
    for (int k = 0; k < BK; ++k) {
      float a[8], b[8];
      *reinterpret_cast<float4*>(&a[0]) =
          *reinterpret_cast<const float4*>(&As[k][ty * 8]);
      *reinterpret_cast<float4*>(&a[4]) =
          *reinterpret_cast<const float4*>(&As[k][ty * 8 + 4]);
      *reinterpret_cast<float4*>(&b[0]) =
          *reinterpret_cast<const float4*>(&Bs[k][tx * 8]);
      *reinterpret_cast<float4*>(&b[4]) =
          *reinterpret_cast<const float4*>(&Bs[k][tx * 8 + 4]);
#pragma unroll
      for (int i = 0; i < 8; ++i)
#pragma unroll
        for (int j = 0; j < 8; ++j) acc[i][j] = fmaf(a[i], b[j], acc[i][j]);
    }
    __syncthreads();
  }

#pragma unroll
  for (int i = 0; i < 8; ++i) {
    size_t row = (size_t)bm * BM + ty * 8 + i;
#pragma unroll
    for (int j = 0; j < 8; j += 4) {
      *reinterpret_cast<float4*>(&C[row * N + bn * BN + tx * 8 + j]) =
          *reinterpret_cast<const float4*>(&acc[i][j]);
    }
  }
}

// ---------------------------------------------------------------------------
// Persistent recurrence: 4-chain wave specialization + flag broadcast.
// 256 WGs x 512 thr (8 waves), 1 WG/CU (guaranteed by VGPR>128).
// WG (p=wg&7, cg=wg>>3): cols m0=cg*32.  Chains c=0..3: group g=4p+c,
// batches b0=2g (2 each).  Waves 0-3 compute (per thread 2b x 2c x 16-way
// k-split; wreg 128 VGPR).  Wave 4+c: sync/stage for chain c.
// Per-producer flags: member writes g_wgf[g][cg]=t-1 after its stores ack;
// consumers poll all 32 member flags with one wave-load + __all (no RMW
// contention, no publish hop).  Data path sc0+sc1 / nt (MALL-coherent).
// ---------------------------------------------------------------------------
__global__ __launch_bounds__(512, 1) void rnn_persist(
    float* __restrict__ out, const float* __restrict__ Ws) {
  const int tid = threadIdx.x;
  const int wg  = blockIdx.x;
  const int p   = wg & 7;
  const int cg  = wg >> 3;
  const int m0  = cg * 32;
  const size_t TN = (size_t)T * N;

  __shared__ __align__(16) float hc[4][2][1028];  // per-chain h slices
  __shared__ float xpl[4][64];                    // per-chain xp tiles
  __shared__ int lflags[128];  // ready[c]=lflags[c*16], cnt[c]=lflags[64+c*16]
  float (*Wq)[1028] = reinterpret_cast<float(*)[1028]>(&hc[0][0][0]);  // 8 rows

  if (tid == 0) {
#pragma unroll
    for (int c = 0; c < 4; ++c) {
      lflags[c * 16] = -1;
      lflags[64 + c * 16] = 0;
    }
  }
  __syncthreads();

  const int l = tid & 63;
  const int v = tid >> 6;           // 0-3 compute, 4-7 sync (chain v-4)
  const int kp = l >> 2;            // k partition (16-way)
  const int c2 = l & 3;
  const int clocal = v * 8 + c2 * 2;  // compute waves: local col pair base

  // ---- W -> wreg in 4 quarters of 8 rows (overlay on h region) ----
  f4 wreg[2][16];
  for (int quarter = 0; quarter < 4; ++quarter) {
    if (tid < 256) {
#pragma unroll
      for (int q = 0; q < 8; ++q)
        *reinterpret_cast<float4*>(&Wq[q][tid * 4]) =
            *reinterpret_cast<const float4*>(
                &Ws[(size_t)(m0 + quarter * 8 + q) * N + tid * 4]);
    }
    __syncthreads();
    if (v == quarter) {
#pragma unroll
      for (int ci = 0; ci < 2; ++ci)
#pragma unroll
        for (int j = 0; j < 16; ++j)
          wreg[ci][j] =
              *reinterpret_cast<const f4*>(&Wq[c2 * 2 + ci][kp * 4 + 64 * j]);
    }
    __syncthreads();
  }

  if (v < 4) {
    // ================= COMPUTE WAVES =================
    for (int t = 0; t < T; ++t) {
#pragma unroll
      for (int c = 0; c < 4; ++c) {
        const int b0 = 8 * p + 2 * c;
        while (*(volatile int*)&lflags[c * 16] < t) __builtin_amdgcn_s_sleep(1);
        __builtin_amdgcn_fence(__ATOMIC_ACQUIRE, "workgroup");
        float acc[4];
#pragma unroll
        for (int i = 0; i < 4; ++i) acc[i] = 0.f;
        if (t > 0) {
#pragma unroll
          for (int j = 0; j < 16; ++j) {
            const int kb = kp * 4 + 64 * j;
            f4 h0 = *reinterpret_cast<const f4*>(&hc[c][0][kb]);
            f4 h1 = *reinterpret_cast<const f4*>(&hc[c][1][kb]);
#pragma unroll
            for (int ci = 0; ci < 2; ++ci) {
              float a0 = acc[ci], a1 = acc[2 + ci];
              a0 = fmaf(h0.x, wreg[ci][j].x, a0);
              a0 = fmaf(h0.y, wreg[ci][j].y, a0);
              a0 = fmaf(h0.z, wreg[ci][j].z, a0);
              a0 = fmaf(h0.w, wreg[ci][j].w, a0);
              a1 = fmaf(h1.x, wreg[ci][j].x, a1);
              a1 = fmaf(h1.y, wreg[ci][j].y, a1);
              a1 = fmaf(h1.z, wreg[ci][j].z, a1);
              a1 = fmaf(h1.w, wreg[ci][j].w, a1);
              acc[ci] = a0;
              acc[2 + ci] = a1;
            }
          }
#pragma unroll
          for (int o = 4; o < 64; o <<= 1)
#pragma unroll
            for (int i = 0; i < 4; ++i) acc[i] += __shfl_xor(acc[i], o, 64);
        }
        if (l < 4) {  // reducer lanes: kp==0, c2==l
#pragma unroll
          for (int bi = 0; bi < 2; ++bi) {
            float x0 = xpl[c][bi * 32 + clocal];
            float x1 = xpl[c][bi * 32 + clocal + 1];
            f2 r;
            r.x = tanhf((t > 0 ? acc[bi * 2 + 0] : 0.f) + x0);
            r.y = tanhf((t > 0 ? acc[bi * 2 + 1] : 0.f) + x1);
            st_sys_x2(out + (size_t)(b0 + bi) * TN + (size_t)t * N + m0 + clocal,
                      r);
          }
        }
        wait_vm0();  // this wave's stores acked at MALL
        if (l == 0) atomicAdd(&lflags[64 + c * 16], 1);
      }
    }
  } else {
    // ================= SYNC/STAGE WAVES (one per chain) =================
    const int c  = v - 4;
    const int g  = 4 * p + c;
    const int b0 = 2 * g;  // = 8p + 2c
    volatile int* ready = (volatile int*)&lflags[c * 16];
    volatile int* cnt   = (volatile int*)&lflags[64 + c * 16];

    const int rr = l >> 5;   // h row 0..1 (32 lanes per row)
    const int cc = l & 31;
    const float* hrow = out + (size_t)(b0 + rr) * TN;
    const int xr = (l >> 3) & 1, xc = (l & 7) * 4;  // lane<16
    const float* xsrc = out + (size_t)(b0 + xr) * TN + m0 + xc;

    // stage xp(0); publish ready=0
    {
      f4 xv;
      if (l < 16) xv = ld_sys_x4(xsrc);
      wait_vm0();
      if (l < 16) *reinterpret_cast<f4*>(&xpl[c][xr * 32 + xc]) = xv;
      __builtin_amdgcn_fence(__ATOMIC_RELEASE, "workgroup");
      if (l == 0) *ready = 0;
    }

    for (int t = 1; t < T; ++t) {
      if (l == 0) {
        while (*cnt < 4 * t) __builtin_amdgcn_s_sleep(1);  // local acks(t-1)
        st_sys_i32(&g_wgf[g][cg].v, t - 1);                // broadcast own flag
      }
      // whole-wave poll of all 32 member flags (read-only, parallel)
      for (;;) {
        int fl = ld_sys_i32(&g_wgf[g][l & 31].v);
        if (__all((l >= 32) || (fl >= t - 1))) break;
        __builtin_amdgcn_s_sleep(1);
      }
      // stage h(t-1) (8 KB) + xp(t), single vmcnt round
      const float* hs = hrow + (size_t)(t - 1) * N;
      f4 tmp[8];
      f4 xv;
#pragma unroll
      for (int q = 0; q < 8; ++q) tmp[q] = ld_sys_x4(hs + 4 * (cc + 32 * q));
      if (l < 16) xv = ld_sys_x4(xsrc + (size_t)t * N);
      wait_vm0();
#pragma unroll
      for (int q = 0; q < 8; ++q)
        *reinterpret_cast<f4*>(&hc[c][rr][4 * (cc + 32 * q)]) = tmp[q];
      if (l < 16) *reinterpret_cast<f4*>(&xpl[c][xr * 32 + xc]) = xv;
      __builtin_amdgcn_fence(__ATOMIC_RELEASE, "workgroup");
      if (l == 0) *ready = t;
    }
  }
}

// ---------------------------------------------------------------------------
extern "C" void kernel_launch(void* const* d_in, const int* in_sizes, int n_in,
                              void* d_out, int out_size, void* d_ws,
                              size_t ws_size, hipStream_t stream) {
  const float* in_seq  = (const float*)d_in[0];  // (64,512,1024)
  const float* W_lower = (const float*)d_in[1];  // (1024,1024)
  const float* W_input = (const float*)d_in[2];  // (1024,1024)
  float* out = (float*)d_out;                    // (64,512,1024)
  float* Ws  = (float*)d_ws;                     // 4 MiB scratch

  symm_k<<<dim3(N / 16, N / 16), 256, 0, stream>>>(W_lower, Ws);
  xproj_gemm<<<dim3(N / 128, (BATCH * T) / 128), 256, 0, stream>>>(
      in_seq, W_input, out, BATCH * T);
  rnn_persist<<<NWG, 512, 0, stream>>>(out, Ws);
}